// Round 2
// baseline (614.977 us; speedup 1.0000x reference)
//
#include <hip/hip_runtime.h>
#include <hip/hip_bf16.h>
#include <cstdint>

typedef unsigned short u16;
typedef __attribute__((ext_vector_type(8))) short bf16x8;
typedef __attribute__((ext_vector_type(4))) float f32x4;

#define BB 64
#define EE 1024
#define HH 1024
#define LLEN 512
#define VV 50257
#define EH 2048
#define H3 3072
#define NCHUNK 16
#define CHUNK 3142  // ceil(50257/16)

__device__ __forceinline__ u16 f2b(float f) {
  union { float f; uint32_t i; } v; v.f = f;
  uint32_t i = v.i;
  uint32_t r = (i + 0x7FFFu + ((i >> 16) & 1u)) >> 16;  // RNE
  return (u16)r;
}
__device__ __forceinline__ float b2f(u16 u) {
  union { uint32_t i; float f; } v; v.i = ((uint32_t)u) << 16; return v.f;
}
__device__ __forceinline__ bf16x8 cvt8(float4 a, float4 b) {
  bf16x8 o;
  o[0] = (short)f2b(a.x); o[1] = (short)f2b(a.y); o[2] = (short)f2b(a.z); o[3] = (short)f2b(a.w);
  o[4] = (short)f2b(b.x); o[5] = (short)f2b(b.y); o[6] = (short)f2b(b.z); o[7] = (short)f2b(b.w);
  return o;
}

// ---- embedding gather + bf16 staging: cat1=[emb|hid], cat2[:, :E]=emb, hbf=bf16(hid)
__global__ void prep_k(const int* __restrict__ ids, const float* __restrict__ embW,
                       const float* __restrict__ hid, u16* __restrict__ cat1,
                       u16* __restrict__ cat2, u16* __restrict__ hbf) {
  int b = blockIdx.x, t = threadIdx.x;
  const float* er = embW + (size_t)ids[b] * EE;
  for (int e = t; e < EE; e += 256) {
    u16 ev = f2b(er[e]);
    cat1[b * EH + e] = ev;
    cat2[b * EH + e] = ev;
    u16 hv = f2b(hid[b * HH + e]);
    cat1[b * EH + EE + e] = hv;
    hbf[b * HH + e] = hv;
  }
}

// ---- MFMA bf16 GEMM: C[64,N] = A_bf16[64,K] * bf16(W_f32[N,K])^T
// MODE 0: fp32 partials [ksplit][64][N] (blockIdx.y = k-split index)
// MODE 1: direct fp32 store with fp32 bias (blockIdx.y == 0, kpc = K/32)
template<int WN, int MODE>
__global__ __launch_bounds__(256) void gemm_k(
    const u16* __restrict__ A, const float* __restrict__ W,
    float* __restrict__ outp, const float* __restrict__ bias,
    int N, int K, int kpc) {
  const int lane = threadIdx.x & 63;
  const int wv = threadIdx.x >> 6;
  const int ml = lane & 15;   // A: m index / W: n index / C: col
  const int q  = lane >> 4;   // k quad
  const int n0 = blockIdx.x * (64 * WN) + wv * (16 * WN);
  const int kc0 = blockIdx.y * kpc;
  f32x4 acc[4][WN];
#pragma unroll
  for (int bt = 0; bt < 4; ++bt)
#pragma unroll
    for (int w = 0; w < WN; ++w) acc[bt][w] = (f32x4){0.f, 0.f, 0.f, 0.f};

  for (int kc = kc0; kc < kc0 + kpc; ++kc) {
    const int kk = kc * 32 + q * 8;
    bf16x8 af[4];
#pragma unroll
    for (int bt = 0; bt < 4; ++bt)
      af[bt] = *(const bf16x8*)(A + (size_t)(bt * 16 + ml) * K + kk);
    bf16x8 wf[WN];
#pragma unroll
    for (int w = 0; w < WN; ++w) {
      int r = n0 + w * 16 + ml;
      int rc = r < N ? r : N - 1;  // clamp: OOB lanes never store, value irrelevant
      const float4* wp = (const float4*)(W + (size_t)rc * K + kk);
      wf[w] = cvt8(wp[0], wp[1]);
    }
#pragma unroll
    for (int bt = 0; bt < 4; ++bt)
#pragma unroll
      for (int w = 0; w < WN; ++w)
        acc[bt][w] = __builtin_amdgcn_mfma_f32_16x16x32_bf16(af[bt], wf[w], acc[bt][w], 0, 0, 0);
  }

#pragma unroll
  for (int bt = 0; bt < 4; ++bt)
#pragma unroll
    for (int w = 0; w < WN; ++w) {
      int n = n0 + w * 16 + ml;
#pragma unroll
      for (int r = 0; r < 4; ++r) {
        int b = bt * 16 + q * 4 + r;  // C row = (lane>>4)*4 + reg within m-tile
        if (MODE == 0) {
          outp[((size_t)blockIdx.y * 64 + b) * N + n] = acc[bt][w][r];
        } else {
          if (n < N)
            outp[(size_t)b * N + n] = acc[bt][w][r] + bias[n];
        }
      }
    }
}

// ---- k-split reduce + bias + optional relu; fp32 and/or bf16 out
__global__ void reduce_k(const float* __restrict__ part, int ks, int count, int N,
                         const float* __restrict__ bias, int relu,
                         float* __restrict__ outF, u16* __restrict__ outB) {
  int idx = blockIdx.x * 256 + threadIdx.x;
  if (idx >= count) return;
  float s = 0.f;
  for (int k = 0; k < ks; ++k) s += part[(size_t)k * count + idx];
  int n = idx % N;
  s += bias[n];
  if (relu) s = fmaxf(s, 0.f);
  if (outF) outF[idx] = s;
  if (outB) outB[idx] = f2b(s);
}

// ---- softmax over L=512 per batch row (fp32)
__global__ void softmax_k(const float* __restrict__ scores, float* __restrict__ aw) {
  int b = blockIdx.x, t = threadIdx.x;
  __shared__ float sd[256];
  float v0 = scores[b * LLEN + t], v1 = scores[b * LLEN + 256 + t];
  float m = fmaxf(v0, v1);
  sd[t] = m; __syncthreads();
  for (int st = 128; st > 0; st >>= 1) { if (t < st) sd[t] = fmaxf(sd[t], sd[t + st]); __syncthreads(); }
  m = sd[0]; __syncthreads();
  float e0 = __expf(v0 - m), e1 = __expf(v1 - m);
  sd[t] = e0 + e1; __syncthreads();
  for (int st = 128; st > 0; st >>= 1) { if (t < st) sd[t] += sd[t + st]; __syncthreads(); }
  float inv = 1.0f / sd[0];
  aw[b * LLEN + t] = e0 * inv;
  aw[b * LLEN + 256 + t] = e1 * inv;
}

// ---- attn_applied partials over fp32 encoder: block = (b, l-chunk of 64)
__global__ void attn_part_k(const float* __restrict__ aw, const float* __restrict__ enc,
                            float* __restrict__ part) {
  int bid = blockIdx.x;  // 512 blocks
  int b = bid >> 3, lc = bid & 7;
  int d0 = threadIdx.x * 4;
  float a0 = 0, a1 = 0, a2 = 0, a3 = 0;
  for (int l = lc * 64; l < lc * 64 + 64; ++l) {
    float w = aw[b * LLEN + l];
    float4 ev = *(const float4*)(enc + ((size_t)b * LLEN + l) * HH + d0);
    a0 += w * ev.x; a1 += w * ev.y; a2 += w * ev.z; a3 += w * ev.w;
  }
  float4 o = {a0, a1, a2, a3};
  *(float4*)(part + ((size_t)(b * 8 + lc)) * HH + d0) = o;
}

__global__ void attn_red_k(const float* __restrict__ part, u16* __restrict__ cat2) {
  int idx = blockIdx.x * 256 + threadIdx.x;  // 65536
  int b = idx >> 10, d = idx & 1023;
  float s = 0.f;
  for (int lc = 0; lc < 8; ++lc) s += part[((size_t)(b * 8 + lc)) * HH + d];
  cat2[b * EH + EE + d] = f2b(s);
}

// ---- GRU gate fusion (torch order r,z,n); hid fp32; nh -> bf16(ws) + fp32(out)
__global__ void gates_k(const float* __restrict__ gi, const float* __restrict__ gh,
                        const float* __restrict__ hid, u16* __restrict__ nhbf,
                        float* __restrict__ outNh) {
  int idx = blockIdx.x * 256 + threadIdx.x;  // 65536
  int b = idx >> 10, j = idx & 1023;
  const float* gib = gi + (size_t)b * H3;
  const float* ghb = gh + (size_t)b * H3;
  float r = 1.f / (1.f + __expf(-(gib[j] + ghb[j])));
  float z = 1.f / (1.f + __expf(-(gib[HH + j] + ghb[HH + j])));
  float n = tanhf(gib[2 * HH + j] + r * ghb[2 * HH + j]);
  float h = hid[idx];
  float v = (1.f - z) * n + z * h;
  nhbf[idx] = f2b(v);
  outNh[idx] = v;
}

// ---- two-phase logsumexp over V (fp32 logits in d_out)
__global__ void lse_part_k(const float* __restrict__ logits, float* __restrict__ pair) {
  int b = blockIdx.y, c = blockIdx.x, t = threadIdx.x;
  const float* row = logits + (size_t)b * VV;
  int v0 = c * CHUNK, v1 = min(VV, v0 + CHUNK);
  __shared__ float sd[256];
  float m = -1e30f;
  for (int v = v0 + t; v < v1; v += 256) m = fmaxf(m, row[v]);
  sd[t] = m; __syncthreads();
  for (int st = 128; st > 0; st >>= 1) { if (t < st) sd[t] = fmaxf(sd[t], sd[t + st]); __syncthreads(); }
  m = sd[0]; __syncthreads();
  float s = 0.f;
  for (int v = v0 + t; v < v1; v += 256) s += __expf(row[v] - m);
  sd[t] = s; __syncthreads();
  for (int st = 128; st > 0; st >>= 1) { if (t < st) sd[t] += sd[t + st]; __syncthreads(); }
  if (t == 0) { pair[(b * NCHUNK + c) * 2] = m; pair[(b * NCHUNK + c) * 2 + 1] = sd[0]; }
}

__global__ void lse2_k(const float* __restrict__ pair, float* __restrict__ lse) {
  int b = blockIdx.x;
  if (threadIdx.x == 0) {
    float M = -1e30f;
    for (int c = 0; c < NCHUNK; ++c) M = fmaxf(M, pair[(b * NCHUNK + c) * 2]);
    float S = 0.f;
    for (int c = 0; c < NCHUNK; ++c)
      S += pair[(b * NCHUNK + c) * 2 + 1] * __expf(pair[(b * NCHUNK + c) * 2] - M);
    lse[b] = M + logf(S);
  }
}

__global__ void final_k(float* __restrict__ logits, const float* __restrict__ lse) {
  int b = blockIdx.y;
  int v = blockIdx.x * 256 + threadIdx.x;
  if (v < VV) {
    size_t i = (size_t)b * VV + v;
    logits[i] = logits[i] - lse[b];
  }
}

extern "C" void kernel_launch(void* const* d_in, const int* in_sizes, int n_in,
                              void* d_out, int out_size, void* d_ws, size_t ws_size,
                              hipStream_t stream) {
  const int*   ids   = (const int*)d_in[0];
  const float* hid   = (const float*)d_in[1];
  const float* enc   = (const float*)d_in[2];
  const float* embW  = (const float*)d_in[3];
  const float* attnW = (const float*)d_in[4];
  const float* attnB = (const float*)d_in[5];
  const float* combW = (const float*)d_in[6];
  const float* combB = (const float*)d_in[7];
  const float* Wih   = (const float*)d_in[8];
  const float* Whh   = (const float*)d_in[9];
  const float* bih   = (const float*)d_in[10];
  const float* bhh   = (const float*)d_in[11];
  const float* outW  = (const float*)d_in[12];
  const float* outB  = (const float*)d_in[13];
  float* out_log = (float*)d_out;                  // [B,V] fp32
  float* out_nh  = out_log + (size_t)BB * VV;      // [B,H] fp32

  char* ws = (char*)d_ws;
  float* U      = (float*)(ws);                // k-split partials, up to 6 MB
  float* apart  = (float*)(ws + 0x600000);     // [64,8,1024] fp32, 2 MB
  u16*   cat1   = (u16*)  (ws + 0x800000);     // [64,2048] bf16
  u16*   cat2   = (u16*)  (ws + 0x840000);     // [64,2048] bf16
  u16*   hbf    = (u16*)  (ws + 0x880000);     // [64,1024] bf16
  float* scores = (float*)(ws + 0x8A0000);     // [64,512]
  float* aw     = (float*)(ws + 0x8C0000);     // [64,512]
  u16*   xbf    = (u16*)  (ws + 0x8E0000);     // [64,1024] bf16
  float* gi     = (float*)(ws + 0x900000);     // [64,3072]
  float* gh     = (float*)(ws + 0x9C0000);     // [64,3072]
  u16*   nhbf   = (u16*)  (ws + 0xA80000);     // [64,1024] bf16
  float* pair   = (float*)(ws + 0xAA0000);     // [64,16,2]
  float* lse    = (float*)(ws + 0xAA4000);     // [64]

  // 1. gather + bf16 staging
  hipLaunchKernelGGL(prep_k, dim3(64), dim3(256), 0, stream, ids, embW, hid, cat1, cat2, hbf);
  // 2-3. attention scores: N=512, K=2048, ksplit=32 (kpc=2)
  hipLaunchKernelGGL((gemm_k<4,0>), dim3(2, 32), dim3(256), 0, stream,
                     cat1, attnW, U, (const float*)nullptr, 512, 2048, 2);
  hipLaunchKernelGGL(reduce_k, dim3(128), dim3(256), 0, stream,
                     U, 32, 64 * 512, 512, attnB, 0, scores, (u16*)nullptr);
  // 4. softmax over L
  hipLaunchKernelGGL(softmax_k, dim3(64), dim3(256), 0, stream, scores, aw);
  // 5-6. attn_applied = aw @ enc -> cat2[:, E:]  (full fp32)
  hipLaunchKernelGGL(attn_part_k, dim3(512), dim3(256), 0, stream, aw, enc, apart);
  hipLaunchKernelGGL(attn_red_k, dim3(256), dim3(256), 0, stream, apart, cat2);
  // 7-8. combine + relu: N=1024, K=2048, ksplit=16 (kpc=4)
  hipLaunchKernelGGL((gemm_k<4,0>), dim3(4, 16), dim3(256), 0, stream,
                     cat2, combW, U, (const float*)nullptr, 1024, 2048, 4);
  hipLaunchKernelGGL(reduce_k, dim3(256), dim3(256), 0, stream,
                     U, 16, 65536, 1024, combB, 1, (float*)nullptr, xbf);
  // 9-12. GRU matmuls: N=3072, K=1024, ksplit=8 (kpc=4)
  hipLaunchKernelGGL((gemm_k<4,0>), dim3(12, 8), dim3(256), 0, stream,
                     xbf, Wih, U, (const float*)nullptr, 3072, 1024, 4);
  hipLaunchKernelGGL(reduce_k, dim3(768), dim3(256), 0, stream,
                     U, 8, 196608, 3072, bih, 0, gi, (u16*)nullptr);
  hipLaunchKernelGGL((gemm_k<4,0>), dim3(12, 8), dim3(256), 0, stream,
                     hbf, Whh, U, (const float*)nullptr, 3072, 1024, 4);
  hipLaunchKernelGGL(reduce_k, dim3(768), dim3(256), 0, stream,
                     U, 8, 196608, 3072, bhh, 0, gh, (u16*)nullptr);
  // 13. gates -> new_hidden (bf16 to ws, fp32 to d_out)
  hipLaunchKernelGGL(gates_k, dim3(256), dim3(256), 0, stream, gi, gh, hid, nhbf, out_nh);
  // 14. vocab projection: N=50257, K=1024, WN=1 -> 786 blocks, fp32 logits + bias
  hipLaunchKernelGGL((gemm_k<1,1>), dim3(786, 1), dim3(256), 0, stream,
                     nhbf, outW, out_log, outB, VV, 1024, 32);
  // 15-17. log_softmax: two-phase LSE then in-place subtract
  hipLaunchKernelGGL(lse_part_k, dim3(16, 64), dim3(256), 0, stream, out_log, pair);
  hipLaunchKernelGGL(lse2_k, dim3(64), dim3(64), 0, stream, pair, lse);
  hipLaunchKernelGGL(final_k, dim3(197, 64), dim3(256), 0, stream, out_log, lse);
}